// Round 10
// baseline (183.997 us; speedup 1.0000x reference)
//
#include <hip/hip_runtime.h>

#define IMG_W 512
#define IMG_H 512
#define N_IMG 48            // 16 batch * 3 channels
#define TILE_W 64
#define TILE_H 32
#define RAD 5
#define XROWS 44            // halo rows 0..41 + 2 pad; m-tiles overlap: {0,12,28}
#define XCOLS 88            // 80 data cols + 8 pad (stride 176B: gcd(44dw,32)=4 -> 2-way, free)
#define YTROWS 56           // 48 used + 8 pad (stride 112B: gcd(28dw,32)=4 -> 2-way)
#define NBX (IMG_W / TILE_W)   // 8
#define NBY (IMG_H / TILE_H)   // 16

typedef float f32x4v __attribute__((ext_vector_type(4)));
typedef short bf16x8 __attribute__((ext_vector_type(8)));

// Gaussian weights (sigma=1.5, normalized) baked as fp32 literals; rel err
// ~1e-7 vs reference's fp32 expf — swamped by bf16 rounding (absmax ~8e-3,
// threshold 2e-2). Kills ~22 expf/thread of prologue VALU (R8 lesson).
__device__ __constant__ float WT[11] = {
    0.00102838f, 0.00759870f, 0.03600080f, 0.10936080f, 0.21300550f,
    0.26601130f, 0.21300550f, 0.10936080f, 0.03600080f, 0.00759870f,
    0.00102838f};

__global__ void ssim_zero_acc(double* acc) {
    if (threadIdx.x == 0) acc[0] = 0.0;
}

// RNE round fp32 -> bf16 bits (manual bit-twiddle; ROCm 7.2 hip_bf16.h has no
// usable __float2bfloat16_rn(float) — R9 compile failure)
__device__ inline unsigned short bf16r(float a) {
    unsigned int u = __float_as_uint(a);
    u = (u + 0x7fffu + ((u >> 16) & 1u)) >> 16;
    return (unsigned short)u;
}
__device__ inline unsigned int bf16pair(float a, float b) {
    unsigned int ua = __float_as_uint(a), ub = __float_as_uint(b);
    ua = (ua + 0x7fffu + ((ua >> 16) & 1u)) >> 16;
    ub = (ub + 0x7fffu + ((ub >> 16) & 1u)) >> 16;
    return ua | (ub << 16);
}

// NOTE 1 (R3/R4 vs R5): NO __threadfence / fold-in finalize. Per-block
// agent-scope fence forces XCD-L2 writeback 6144x/dispatch; dur triples.
// NOTE 2 (R6): launch_bounds min-waves stays 4; (256,6) spilled 67MB.
// NOTE 3 (R8): both 11-tap convs on MFMA (data in A, banded weights in B;
// C/D layout gives the V-pass transpose for free via b64 YT writes).
// NOTE 4 (R9): LDS strides padded to gcd(stride_dw,32)=4 -> 2-way bank
// aliasing (free, m136). R8's 160B/96B strides were gcd=8 -> 4-way, 4.4M
// conflict cycles.
__global__ __launch_bounds__(256, 4)
void ssim_main(const float* __restrict__ pred, const float* __restrict__ targ,
               double* __restrict__ acc)
{
    __shared__ __align__(16) union {
        unsigned short X [5][XROWS][XCOLS];    // [arr][halo row][ci], ci = imgcol-col0+8
        unsigned short YT[5][TILE_W][YTROWS];  // [arr][tile col][halo row]
    } sh;
    __shared__ float wave_part[4];

    const int tid  = threadIdx.x;
    const int lane = tid & 63;
    const int wv   = tid >> 6;     // wave 0..3
    const int n15  = lane & 15;
    const int q    = lane >> 4;    // 0..3

    // B fragments: lane holds B[k][n], n=lane&15, k=q*8+j.
    // Hconv: tap d = k - n - 3; Vconv: d = k - n (n-tile1 reuses via K-window
    // shifted 16 rows). Out-of-band -> 0.
    bf16x8 Bh, Bv;
    #pragma unroll
    for (int j = 0; j < 8; ++j) {
        const int k = q * 8 + j;
        const int dh = k - n15 - 3;
        const int dv = k - n15;
        Bh[j] = (dh >= 0 && dh <= 10) ? (short)bf16r(WT[dh]) : (short)0;
        Bv[j] = (dv >= 0 && dv <= 10) ? (short)bf16r(WT[dv]) : (short)0;
    }

    const int col0 = blockIdx.x * TILE_W;
    const int row0 = blockIdx.y * TILE_H;
    const bool edge = (blockIdx.x == 0) || (blockIdx.x == NBX - 1);
    const long img = blockIdx.z;
    const float* __restrict__ p = pred + img * (long)(IMG_H * IMG_W);
    const float* __restrict__ t = targ + img * (long)(IMG_H * IMG_W);

    // ---- Phase 0: stage {p,t,pp,tt,pt} bf16 into X, zero outside image.
    // Data cols 0..79 written; pad cols 80..87 never read (max k idx = 79).
    for (int idx = tid; idx < XROWS * 20; idx += 256) {   // 880 items
        const int r = idx / 20;
        const int g = idx - r * 20;
        const int gr  = row0 - RAD + r;
        const int gcb = col0 - 8 + 4 * g;
        float pv[4] = {0.f, 0.f, 0.f, 0.f};
        float tv[4] = {0.f, 0.f, 0.f, 0.f};
        if (gr >= 0 && gr < IMG_H) {
            const float* __restrict__ prow = p + (long)gr * IMG_W;
            const float* __restrict__ trow = t + (long)gr * IMG_W;
            if (!edge || (gcb >= 0 && gcb + 4 <= IMG_W)) {
                const float4 a = *(const float4*)&prow[gcb];
                const float4 b = *(const float4*)&trow[gcb];
                pv[0] = a.x; pv[1] = a.y; pv[2] = a.z; pv[3] = a.w;
                tv[0] = b.x; tv[1] = b.y; tv[2] = b.z; tv[3] = b.w;
            } else {
                #pragma unroll
                for (int e = 0; e < 4; ++e) {
                    const int c = gcb + e;
                    if (c >= 0 && c < IMG_W) { pv[e] = prow[c]; tv[e] = trow[c]; }
                }
            }
        }
        *(uint2*)&sh.X[0][r][4 * g] = make_uint2(bf16pair(pv[0], pv[1]), bf16pair(pv[2], pv[3]));
        *(uint2*)&sh.X[1][r][4 * g] = make_uint2(bf16pair(tv[0], tv[1]), bf16pair(tv[2], tv[3]));
        *(uint2*)&sh.X[2][r][4 * g] = make_uint2(bf16pair(pv[0]*pv[0], pv[1]*pv[1]),
                                                 bf16pair(pv[2]*pv[2], pv[3]*pv[3]));
        *(uint2*)&sh.X[3][r][4 * g] = make_uint2(bf16pair(tv[0]*tv[0], tv[1]*tv[1]),
                                                 bf16pair(tv[2]*tv[2], tv[3]*tv[3]));
        *(uint2*)&sh.X[4][r][4 * g] = make_uint2(bf16pair(pv[0]*tv[0], pv[1]*tv[1]),
                                                 bf16pair(pv[2]*tv[2], pv[3]*tv[3]));
    }
    __syncthreads();

    // ---- MFMA pass 1: horizontal conv. Wave wv owns out-col tile wv.
    // m-tiles at row offsets {0,12,28} (overlap regions produce identical
    // values -> duplicate YT writes are benign). Keeps XROWS=44 so the
    // padded XCOLS=88 stride still fits 4 blocks/CU.
    uint2 yreg[15];
    {
        const f32x4v cz = {0.f, 0.f, 0.f, 0.f};
        int i = 0;
        #pragma unroll
        for (int a = 0; a < 5; ++a) {
            #pragma unroll
            for (int mt = 0; mt < 3; ++mt) {
                const int toff = (mt == 0) ? 0 : (mt == 1) ? 12 : 28;
                const bf16x8 A = *(const bf16x8*)&sh.X[a][toff + n15][wv * 16 + 8 * q];
                const f32x4v c = __builtin_amdgcn_mfma_f32_16x16x32_bf16(A, Bh, cz, 0, 0, 0);
                yreg[i++] = make_uint2(bf16pair(c[0], c[1]), bf16pair(c[2], c[3]));
            }
        }
    }
    __syncthreads();   // all X reads complete; union space becomes YT
    {
        int i = 0;
        #pragma unroll
        for (int a = 0; a < 5; ++a)
            #pragma unroll
            for (int mt = 0; mt < 3; ++mt) {
                const int toff = (mt == 0) ? 0 : (mt == 1) ? 12 : 28;
                *(uint2*)&sh.YT[a][wv * 16 + n15][toff + 4 * q] = yreg[i++];
            }
        // zero-fill YT rows 44..47: read by nt=1 K-window with zero weight,
        // must be finite (uninitialized LDS could hold Inf/NaN bit patterns).
        for (int idx = tid; idx < 5 * TILE_W; idx += 256) {
            const int a = idx >> 6;
            const int c = idx & 63;
            *(uint2*)&sh.YT[a][c][44] = make_uint2(0u, 0u);
        }
    }
    __syncthreads();

    // ---- MFMA pass 2: vertical conv. Wave wv owns image-col tile wv.
    f32x4v accv[2][5];
    {
        const f32x4v cz = {0.f, 0.f, 0.f, 0.f};
        #pragma unroll
        for (int nt = 0; nt < 2; ++nt)
            #pragma unroll
            for (int a = 0; a < 5; ++a) {
                const bf16x8 A = *(const bf16x8*)&sh.YT[a][wv * 16 + n15][nt * 16 + 8 * q];
                accv[nt][a] = __builtin_amdgcn_mfma_f32_16x16x32_bf16(A, Bv, cz, 0, 0, 0);
            }
    }

    // ---- SSIM on 8 pixels/lane, fp32 ----
    float lsum = 0.f;
    #pragma unroll
    for (int nt = 0; nt < 2; ++nt) {
        const f32x4v m1 = accv[nt][0], m2 = accv[nt][1];
        const f32x4v epp = accv[nt][2], ett = accv[nt][3], ept = accv[nt][4];
        const f32x4v m1s = m1 * m1, m2s = m2 * m2, m12 = m1 * m2;
        const f32x4v num = (2.f * m12 + 1e-4f) * (2.f * (ept - m12) + 9e-4f);
        const f32x4v den = (m1s + m2s + 1e-4f) * ((epp - m1s) + (ett - m2s) + 9e-4f);
        lsum += num[0] * __builtin_amdgcn_rcpf(den[0]);
        lsum += num[1] * __builtin_amdgcn_rcpf(den[1]);
        lsum += num[2] * __builtin_amdgcn_rcpf(den[2]);
        lsum += num[3] * __builtin_amdgcn_rcpf(den[3]);
    }

    // ---- Block reduction -> one double atomic per block ----
    #pragma unroll
    for (int off = 32; off > 0; off >>= 1)
        lsum += __shfl_down(lsum, off, 64);
    if (lane == 0) wave_part[wv] = lsum;
    __syncthreads();
    if (tid == 0) {
        const float bs = wave_part[0] + wave_part[1] + wave_part[2] + wave_part[3];
        atomicAdd(acc, (double)bs);
    }
}

__global__ void ssim_final(const double* __restrict__ acc, float* __restrict__ out) {
    if (threadIdx.x == 0) {
        const double n = (double)N_IMG * (double)IMG_H * (double)IMG_W;
        out[0] = (float)(1.0 - acc[0] / n);
    }
}

extern "C" void kernel_launch(void* const* d_in, const int* in_sizes, int n_in,
                              void* d_out, int out_size, void* d_ws, size_t ws_size,
                              hipStream_t stream) {
    const float* pred = (const float*)d_in[0];
    const float* targ = (const float*)d_in[1];
    float* out  = (float*)d_out;
    double* acc = (double*)d_ws;

    hipLaunchKernelGGL(ssim_zero_acc, dim3(1), dim3(1), 0, stream, acc);
    dim3 grid(NBX, NBY, N_IMG);   // (8, 16, 48)
    hipLaunchKernelGGL(ssim_main, grid, dim3(256), 0, stream, pred, targ, acc);
    hipLaunchKernelGGL(ssim_final, dim3(1), dim3(1), 0, stream, acc, out);
}